// Round 1
// 265.431 us; speedup vs baseline: 1.0052x; 1.0052x over previous
//
#include <hip/hip_runtime.h>

// Static problem config (from reference):
//   HEIGHT=WIDTH=64, NUM_FRAMES=16, DIM=1280
//   GRIDS: (8,32,32) (16,16,16) (4,48,48) (1,64,64)
//   token offsets: 0, 8192, 12288, 21504, total 25600
//
// ws layout (float elements):
//   pe32 [32*32][1280] @ 0         (1,310,720)
//   pe16 [16*16][1280] @ 1,310,720 (  327,680)
//   pe48 [48*48][1280] @ 1,638,400 (2,949,120)
//   total 4,587,520 floats = 17.5 MiB

#define PE32_OFF 0
#define PE16_OFF 1310720
#define PE48_OFF 1638400

typedef float f32x4 __attribute__((ext_vector_type(4)));

__device__ __forceinline__ float keys_cubic(float x) {
    x = fabsf(x);
    if (x >= 2.0f) return 0.0f;
    if (x >= 1.0f) return ((-0.5f * x + 2.5f) * x - 4.0f) * x + 2.0f;
    return ((1.5f * x - 2.5f) * x) * x + 1.0f;
}

// jax.image.resize 'bicubic', antialias=True, downsample 64 -> out_size.
__device__ __forceinline__ void tap_params(int o, int out_size,
                                           int& i0, int& n, float& sf,
                                           float& inv_ks, float& inv_sum) {
    float inv_scale = 64.0f / (float)out_size;   // > 1 for all our cases
    float ks = inv_scale;                        // kernel_scale = max(inv_scale,1)
    float radius = 2.0f * ks;
    sf = ((float)o + 0.5f) * inv_scale - 0.5f;
    int lo = (int)ceilf(sf - radius); if (lo < 0) lo = 0;
    int hi = (int)floorf(sf + radius); if (hi > 63) hi = 63;
    n = hi - lo + 1;
    i0 = lo;
    inv_ks = 1.0f / ks;
    float sum = 0.0f;
    for (int k = 0; k < n; ++k)
        sum += keys_cubic((sf - (float)(lo + k)) * inv_ks);
    inv_sum = 1.0f / sum;
}

// Fused separable bicubic resize: weight[64][64][1280] -> pe{32,16,48} in ws.
// One block per (output row oy of one sample, 64-channel d-tile).
// Tap coefficients (with 1/sum folded in) are computed ONCE per block into
// LDS (vertical: wave 3, horizontal table: wave 0), so the hot loops are
// pure load+FMA.
// Grid: 96 rows * 20 d-tiles = 1920 blocks x 256 threads.
#define TMP_STRIDE 68
#define MAXTAP 17   // worst case: out=16 -> radius 8 -> up to 17 taps
__global__ __launch_bounds__(256) void resize2d_kernel(const float* __restrict__ weight,
                                                       float* __restrict__ ws) {
    int td  = blockIdx.x % 20;
    int row = blockIdx.x / 20;
    int out_h, out_w, oy; float* pe_base;
    if (row < 32)      { out_h = 32; out_w = 32; oy = row;      pe_base = ws + PE32_OFF; }
    else if (row < 48) { out_h = 16; out_w = 16; oy = row - 32; pe_base = ws + PE16_OFF; }
    else               { out_h = 48; out_w = 48; oy = row - 48; pe_base = ws + PE48_OFF; }
    int d0 = td * 64;

    __shared__ float tmp[64 * TMP_STRIDE];
    __shared__ float vcoef[MAXTAP];
    __shared__ int   vmeta[2];                 // i0, n
    __shared__ float hcoef[48][MAXTAP + 1];    // stride 18 floats (bank spread)
    __shared__ int   hj0[48];
    __shared__ int   hn[48];

    int tid = threadIdx.x;

    // Vertical taps for this row: one thread in wave 3 (overlaps with wave 0's work).
    if (tid == 192) {
        int i0, n; float sf, ik, is;
        tap_params(oy, out_h, i0, n, sf, ik, is);
        vmeta[0] = i0; vmeta[1] = n;
        for (int k = 0; k < n; ++k)
            vcoef[k] = keys_cubic((sf - (float)(i0 + k)) * ik) * is;
    }
    // Horizontal tap table: one thread per output column (out_w <= 48, all in wave 0).
    if (tid < out_w) {
        int j0, n; float sf, ik, is;
        tap_params(tid, out_w, j0, n, sf, ik, is);
        hj0[tid] = j0; hn[tid] = n;
        for (int k = 0; k < n; ++k)
            hcoef[tid][k] = keys_cubic((sf - (float)(j0 + k)) * ik) * is;
    }
    __syncthreads();

    // Stage 1: vertical (H) resize for this output row into LDS.
    int i0 = vmeta[0], nh = vmeta[1];
    for (int item = tid; item < 1024; item += 256) {
        int x  = item >> 4;        // 0..63 source column
        int f4 = item & 15;        // which float4 of the 64-ch tile
        const float* src = weight + (size_t)x * 1280 + d0 + (f4 << 2);
        float4 acc = make_float4(0.f, 0.f, 0.f, 0.f);
        for (int k = 0; k < nh; ++k) {
            float c = vcoef[k];    // broadcast, conflict-free
            float4 v = *(const float4*)(src + (size_t)(i0 + k) * (64 * 1280));
            acc.x += c * v.x; acc.y += c * v.y; acc.z += c * v.z; acc.w += c * v.w;
        }
        *(float4*)&tmp[x * TMP_STRIDE + (f4 << 2)] = acc;
    }
    __syncthreads();

    // Stage 2: horizontal (W) resize out of LDS, write pe row.
    int nitems = out_w << 4;
    for (int item = tid; item < nitems; item += 256) {
        int ox = item >> 4;
        int f4 = item & 15;
        int j0 = hj0[ox], nw = hn[ox];
        float4 acc = make_float4(0.f, 0.f, 0.f, 0.f);
        for (int k = 0; k < nw; ++k) {
            float c = hcoef[ox][k];
            float4 v = *(const float4*)&tmp[(j0 + k) * TMP_STRIDE + (f4 << 2)];
            acc.x += c * v.x; acc.y += c * v.y; acc.z += c * v.z; acc.w += c * v.w;
        }
        *(float4*)(pe_base + (size_t)(oy * out_w + ox) * 1280 + d0 + (f4 << 2)) = acc;
    }
}

// out[token][d] = x + pe2d[pixel] (+ time_weight[frame] if t > 1).
// 2 float4 (8 floats) per thread; pairs never straddle a token (320 f4/token
// is even). x loads and out stores are nontemporal: each byte is touched
// exactly once, so bypassing cache keeps pe/weight hot in L2/L3.
// 25600*160 = 4,096,000 pairs; grid 16000 x 256.
__global__ __launch_bounds__(256) void add_pe_kernel(const float* __restrict__ x,
                                                     const float* __restrict__ weight,
                                                     const float* __restrict__ tw,
                                                     const float* __restrict__ ws,
                                                     float* __restrict__ out) {
    int p = blockIdx.x * 256 + threadIdx.x;   // pair index (2 consecutive float4s)
    int token = p / 160;                      // 160 pairs per token
    int d = (p - token * 160) << 3;

    const float* pe;
    int frame;
    if (token < 8192) {            // sample 0: t=8, 32x32
        frame = token >> 10;
        int px = token & 1023;
        pe = ws + PE32_OFF + (size_t)px * 1280;
    } else if (token < 12288) {    // sample 1: t=16, 16x16
        int l = token - 8192;
        frame = l >> 8;
        int px = l & 255;
        pe = ws + PE16_OFF + (size_t)px * 1280;
    } else if (token < 21504) {    // sample 2: t=4, 48x48
        int l = token - 12288;
        frame = l / 2304;
        int px = l - frame * 2304;
        pe = ws + PE48_OFF + (size_t)px * 1280;
    } else {                       // sample 3: t=1, 64x64 -> weight directly, NO time add
        int l = token - 21504;
        frame = -1;
        pe = weight + (size_t)l * 1280;
    }

    size_t off = (size_t)token * 1280 + d;
    f32x4 x0 = __builtin_nontemporal_load((const f32x4*)(x + off));
    f32x4 x1 = __builtin_nontemporal_load((const f32x4*)(x + off + 4));
    f32x4 p0 = *(const f32x4*)(pe + d);
    f32x4 p1 = *(const f32x4*)(pe + d + 4);
    f32x4 o0 = x0 + p0;
    f32x4 o1 = x1 + p1;
    if (frame >= 0) {
        f32x4 t0 = *(const f32x4*)(tw + (size_t)frame * 1280 + d);
        f32x4 t1 = *(const f32x4*)(tw + (size_t)frame * 1280 + d + 4);
        o0 += t0;
        o1 += t1;
    }
    __builtin_nontemporal_store(o0, (f32x4*)(out + off));
    __builtin_nontemporal_store(o1, (f32x4*)(out + off + 4));
}

extern "C" void kernel_launch(void* const* d_in, const int* in_sizes, int n_in,
                              void* d_out, int out_size, void* d_ws, size_t ws_size,
                              hipStream_t stream) {
    const float* x      = (const float*)d_in[0];   // [25600,1280]
    const float* weight = (const float*)d_in[1];   // [64,64,1280]
    const float* tw     = (const float*)d_in[2];   // [16,1280]
    // d_in[3] = grid_thws (static metadata, hard-coded)
    float* ws  = (float*)d_ws;
    float* out = (float*)d_out;

    hipLaunchKernelGGL(resize2d_kernel, dim3(1920), dim3(256), 0, stream, weight, ws);
    hipLaunchKernelGGL(add_pe_kernel, dim3(16000), dim3(256), 0, stream, x, weight, tw, ws, out);
}

// Round 4
// 262.908 us; speedup vs baseline: 1.0149x; 1.0096x over previous
//
#include <hip/hip_runtime.h>

// Static problem config (from reference):
//   HEIGHT=WIDTH=64, NUM_FRAMES=16, DIM=1280
//   GRIDS: (8,32,32) (16,16,16) (4,48,48) (1,64,64)
//   token offsets: 0, 8192, 12288, 21504, total 25600
//
// FULLY FUSED: one kernel. Each block owns (one output row of one sample,
// one 64-channel d-tile), resizes that row into LDS (separable bicubic,
// identical math to jax.image.resize bicubic/antialias), then streams
// out = x + pe + tw over all t frames. No workspace intermediate at all.
//
// Row map (160 rows x 20 d-tiles = 3200 blocks):
//   rows  0..31  sample 0: 32x32, t=8,  tok_off 0,     hw 1024
//   rows 32..47  sample 1: 16x16, t=16, tok_off 8192,  hw 256
//   rows 48..95  sample 2: 48x48, t=4,  tok_off 12288, hw 2304
//   rows 96..159 sample 3: 64x64, t=1,  tok_off 21504  (pe = weight, no tw)

__device__ __forceinline__ float keys_cubic(float x) {
    x = fabsf(x);
    if (x >= 2.0f) return 0.0f;
    if (x >= 1.0f) return ((-0.5f * x + 2.5f) * x - 4.0f) * x + 2.0f;
    return ((1.5f * x - 2.5f) * x) * x + 1.0f;
}

// jax.image.resize 'bicubic', antialias=True, downsample 64 -> out_size.
__device__ __forceinline__ void tap_params(int o, int out_size,
                                           int& i0, int& n, float& sf,
                                           float& inv_ks, float& inv_sum) {
    float inv_scale = 64.0f / (float)out_size;   // > 1 for all our cases
    float ks = inv_scale;                        // kernel_scale = max(inv_scale,1)
    float radius = 2.0f * ks;
    sf = ((float)o + 0.5f) * inv_scale - 0.5f;
    int lo = (int)ceilf(sf - radius); if (lo < 0) lo = 0;
    int hi = (int)floorf(sf + radius); if (hi > 63) hi = 63;
    n = hi - lo + 1;
    i0 = lo;
    inv_ks = 1.0f / ks;
    float sum = 0.0f;
    for (int k = 0; k < n; ++k)
        sum += keys_cubic((sf - (float)(lo + k)) * inv_ks);
    inv_sum = 1.0f / sum;
}

#define TMP_STRIDE 68
#define PE_STRIDE  68
#define MAXTAP 17   // worst case: out=16 -> radius 8 -> up to 17 taps

__global__ __launch_bounds__(256) void fused_pe_kernel(const float* __restrict__ x,
                                                       const float* __restrict__ weight,
                                                       const float* __restrict__ tw,
                                                       float* __restrict__ out) {
    __shared__ float tmp[64 * TMP_STRIDE];        // H-resized row: [src col][64 ch]
    __shared__ float pe_lds[48 * PE_STRIDE];      // final pe row:  [out col][64 ch]
    __shared__ float vcoef[MAXTAP];
    __shared__ int   vmeta[2];                    // i0, n
    __shared__ float hcoef[48][MAXTAP + 1];       // stride 18 floats
    __shared__ int   hj0[48];
    __shared__ int   hn[48];

    int td  = blockIdx.x % 20;
    int row = blockIdx.x / 20;
    int d0  = td * 64;
    int tid = threadIdx.x;

    if (row >= 96) {
        // ---- sample 3: identity pe (weight row), single frame, no tw ----
        int oy = row - 96;
        const float* wrow = weight + (size_t)oy * 64 * 1280 + d0;
        size_t obase = (size_t)(21504 + oy * 64) * 1280 + d0;
        for (int item = tid; item < 1024; item += 256) {
            int ox = item >> 4, f4 = item & 15;
            size_t xo = obase + (size_t)ox * 1280 + (f4 << 2);
            float4 xv = *(const float4*)(x + xo);
            float4 pv = *(const float4*)(wrow + (size_t)ox * 1280 + (f4 << 2));
            float4 o = make_float4(xv.x + pv.x, xv.y + pv.y, xv.z + pv.z, xv.w + pv.w);
            *(float4*)(out + xo) = o;
        }
    } else {
        // ---- resize samples ----
        int out_h, out_w, oy, t, tok_off, hw;
        if (row < 32)      { out_h = 32; out_w = 32; oy = row;      t = 8;  tok_off = 0;     hw = 1024; }
        else if (row < 48) { out_h = 16; out_w = 16; oy = row - 32; t = 16; tok_off = 8192;  hw = 256;  }
        else               { out_h = 48; out_w = 48; oy = row - 48; t = 4;  tok_off = 12288; hw = 2304; }

        // Tap tables (1/sum folded in). Vertical: one thread in wave 3;
        // horizontal: one thread per output column (all in wave 0).
        if (tid == 192) {
            int i0, n; float sf, ik, is;
            tap_params(oy, out_h, i0, n, sf, ik, is);
            vmeta[0] = i0; vmeta[1] = n;
            for (int k = 0; k < n; ++k)
                vcoef[k] = keys_cubic((sf - (float)(i0 + k)) * ik) * is;
        }
        if (tid < out_w) {
            int j0, n; float sf, ik, is;
            tap_params(tid, out_w, j0, n, sf, ik, is);
            hj0[tid] = j0; hn[tid] = n;
            for (int k = 0; k < n; ++k)
                hcoef[tid][k] = keys_cubic((sf - (float)(j0 + k)) * ik) * is;
        }
        __syncthreads();

        // Stage 1: vertical (H) resize of this output row into tmp.
        int i0 = vmeta[0], nh = vmeta[1];
        for (int item = tid; item < 1024; item += 256) {
            int sx = item >> 4;        // 0..63 source column
            int f4 = item & 15;
            const float* src = weight + (size_t)sx * 1280 + d0 + (f4 << 2);
            float4 acc = make_float4(0.f, 0.f, 0.f, 0.f);
            for (int k = 0; k < nh; ++k) {
                float c = vcoef[k];    // broadcast, conflict-free
                float4 v = *(const float4*)(src + (size_t)(i0 + k) * (64 * 1280));
                acc.x += c * v.x; acc.y += c * v.y; acc.z += c * v.z; acc.w += c * v.w;
            }
            *(float4*)&tmp[sx * TMP_STRIDE + (f4 << 2)] = acc;
        }
        __syncthreads();

        // Stage 2: horizontal (W) resize from tmp into pe_lds.
        for (int item = tid; item < (out_w << 4); item += 256) {
            int ox = item >> 4;
            int f4 = item & 15;
            int j0 = hj0[ox], nw = hn[ox];
            float4 acc = make_float4(0.f, 0.f, 0.f, 0.f);
            for (int k = 0; k < nw; ++k) {
                float c = hcoef[ox][k];
                float4 v = *(const float4*)&tmp[(j0 + k) * TMP_STRIDE + (f4 << 2)];
                acc.x += c * v.x; acc.y += c * v.y; acc.z += c * v.z; acc.w += c * v.w;
            }
            *(float4*)&pe_lds[ox * PE_STRIDE + (f4 << 2)] = acc;
        }
        __syncthreads();

        // Stage 3: stream out = x + pe + tw over all t frames.
        // Frame-outer / column-inner: no divisions in the hot loop.
        size_t rbase = (size_t)(tok_off + oy * out_w) * 1280 + d0;
        int nitems = out_w << 4;
        for (int f = 0; f < t; ++f) {
            size_t fbase = rbase + (size_t)f * hw * 1280;
            const float* twf = tw + (size_t)f * 1280 + d0;
            for (int item = tid; item < nitems; item += 256) {
                int ox = item >> 4;
                int f4 = item & 15;
                size_t xo = fbase + (size_t)ox * 1280 + (f4 << 2);
                float4 xv = *(const float4*)(x + xo);
                float4 pv = *(const float4*)&pe_lds[ox * PE_STRIDE + (f4 << 2)];
                float4 tv = *(const float4*)(twf + (f4 << 2));
                float4 o = make_float4(xv.x + pv.x + tv.x, xv.y + pv.y + tv.y,
                                       xv.z + pv.z + tv.z, xv.w + pv.w + tv.w);
                *(float4*)(out + xo) = o;
            }
        }
    }
}

extern "C" void kernel_launch(void* const* d_in, const int* in_sizes, int n_in,
                              void* d_out, int out_size, void* d_ws, size_t ws_size,
                              hipStream_t stream) {
    const float* x      = (const float*)d_in[0];   // [25600,1280]
    const float* weight = (const float*)d_in[1];   // [64,64,1280]
    const float* tw     = (const float*)d_in[2];   // [16,1280]
    // d_in[3] = grid_thws (static metadata, hard-coded)
    float* out = (float*)d_out;

    hipLaunchKernelGGL(fused_pe_kernel, dim3(3200), dim3(256), 0, stream,
                       x, weight, tw, out);
}